// Round 2
// baseline (282.192 us; speedup 1.0000x reference)
//
#include <hip/hip_runtime.h>
#include <stdint.h>
#include <math.h>

#define BB 512
#define RR 20
#define LL 50
#define DD 64
#define PP 2
#define KK 10
#define IN_DIM 256   // 2*P*D

// ---------------- threefry2x32 (bit-exact JAX) ----------------
__device__ __forceinline__ uint32_t rotl32(uint32_t v, int d) {
  return (v << d) | (v >> (32 - d));
}

__device__ __forceinline__ void tf2x32(uint32_t k0, uint32_t k1,
                                       uint32_t x0, uint32_t x1,
                                       uint32_t& o0, uint32_t& o1) {
  uint32_t ks0 = k0, ks1 = k1, ks2 = k0 ^ k1 ^ 0x1BD11BDAu;
  x0 += ks0; x1 += ks1;
#define TF_RND(r) { x0 += x1; x1 = rotl32(x1, r); x1 ^= x0; }
  TF_RND(13) TF_RND(15) TF_RND(26) TF_RND(6)
  x0 += ks1; x1 += ks2 + 1u;
  TF_RND(17) TF_RND(29) TF_RND(16) TF_RND(24)
  x0 += ks2; x1 += ks0 + 2u;
  TF_RND(13) TF_RND(15) TF_RND(26) TF_RND(6)
  x0 += ks0; x1 += ks1 + 3u;
  TF_RND(17) TF_RND(29) TF_RND(16) TF_RND(24)
  x0 += ks1; x1 += ks2 + 4u;
  TF_RND(13) TF_RND(15) TF_RND(26) TF_RND(6)
  x0 += ks2; x1 += ks0 + 5u;
#undef TF_RND
  o0 = x0; o1 = x1;
}

// ---------------- K1: embedding sum + gating ----------------
// grid = 2*B*R blocks, 64 threads. block -> (user/item, b, r)
__global__ __launch_bounds__(64) void embed_gate(
    const int* __restrict__ uidx, const int* __restrict__ iidx,
    const float* __restrict__ emb,
    const float* __restrict__ w1, const float* __restrict__ w2,
    const float* __restrict__ b2, const float* __restrict__ bg,
    float* __restrict__ u_rev, float* __restrict__ i_rev) {
  int bid = blockIdx.x;
  int ui = bid / (BB * RR);
  int t  = bid % (BB * RR);
  const int* idx = (ui ? iidx : uidx) + (size_t)t * LL;
  int d = threadIdx.x;
  __shared__ float us[DD];
  float s = 0.f;
  for (int l = 0; l < LL; ++l) {
    int v = idx[l];
    s += emb[(size_t)v * DD + d];
  }
  us[d] = s;
  __syncthreads();
  float dot1 = 0.f, dot2 = 0.f;
  const float* w1r = w1 + d * DD;
  const float* w2r = w2 + d * DD;
  for (int e = 0; e < DD; ++e) {
    float xv = us[e];
    dot1 += xv * w1r[e];
    dot2 += xv * w2r[e];
  }
  float sig = 1.f / (1.f + expf(-dot1));
  float val = sig + bg[d] * tanhf(dot2 + b2[d]);
  float* dst = (ui ? i_rev : u_rev);
  dst[(size_t)t * DD + d] = val;
}

// ---------------- K2: review-level co-attention -> row/col max logits ----------------
// grid = B blocks, 256 threads
__global__ __launch_bounds__(256) void coatt_rev(
    const float* __restrict__ u_rev, const float* __restrict__ i_rev,
    const float* __restrict__ ra_w, const float* __restrict__ ra_b,
    const float* __restrict__ ra_M,
    float* __restrict__ row_logits, float* __restrict__ col_logits) {
  int b = blockIdx.x;
  __shared__ float ur[RR][DD], ir[RR][DD], uo[RR][DD], io[RR][DD], au[RR][DD];
  __shared__ float sc[RR][RR];
  int tid = threadIdx.x;
  for (int i = tid; i < RR * DD; i += 256) {
    ur[i / DD][i % DD] = u_rev[(size_t)b * RR * DD + i];
    ir[i / DD][i % DD] = i_rev[(size_t)b * RR * DD + i];
  }
  __syncthreads();
  for (int i = tid; i < RR * DD; i += 256) {
    int u = i / DD, d = i % DD;
    float a1 = ra_b[d], a2 = ra_b[d];
    const float* wr_ = ra_w + d * DD;
    for (int e = 0; e < DD; ++e) {
      a1 += ur[u][e] * wr_[e];
      a2 += ir[u][e] * wr_[e];
    }
    uo[u][d] = fmaxf(a1, 0.f);
    io[u][d] = fmaxf(a2, 0.f);
  }
  __syncthreads();
  for (int i = tid; i < RR * DD; i += 256) {
    int u = i / DD, e = i % DD;
    float a = 0.f;
    for (int d2 = 0; d2 < DD; ++d2) a += uo[u][d2] * ra_M[d2 * DD + e];
    au[u][e] = a;
  }
  __syncthreads();
  for (int i = tid; i < RR * RR; i += 256) {
    int u = i / RR, v = i % RR;
    float a = 0.f;
    for (int e = 0; e < DD; ++e) a += au[u][e] * io[v][e];
    sc[u][v] = a;
  }
  __syncthreads();
  if (tid < RR) {
    float m = -INFINITY;
    for (int v = 0; v < RR; ++v) m = fmaxf(m, sc[tid][v]);
    row_logits[b * RR + tid] = m;
  } else if (tid >= 64 && tid < 64 + RR) {
    int v = tid - 64;
    float m = -INFINITY;
    for (int u = 0; u < RR; ++u) m = fmaxf(m, sc[u][v]);
    col_logits[b * RR + v] = m;
  }
}

// ---------------- K3: gumbel + argmax selection ----------------
// grid = 4 blocks (n = 2p+which; which 0=row,1=col), 512 threads (thread = b)
// JAX partitionable threefry (default since 0.4.30): for a 32-bit draw at flat
// index e, counter = 64-bit iota split into (hi,lo)=(0,e); bits = o0 ^ o1.
__global__ __launch_bounds__(512) void gumbel_select(
    const float* __restrict__ row_logits, const float* __restrict__ col_logits,
    int* __restrict__ sel) {
  int n = blockIdx.x;
  int b = threadIdx.x;
  uint32_t k0, k1;
  tf2x32(0u, 42u, 0u, (uint32_t)n, k0, k1);  // fold_in(key(42), n)
  const float* logits = (n & 1) ? col_logits : row_logits;
  const float TINY = 1.1754943508222875e-38f;
  float best = -INFINITY;
  int argr = 0;
  for (int r = 0; r < RR; ++r) {
    int e = b * RR + r;
    uint32_t o0, o1;
    tf2x32(k0, k1, 0u, (uint32_t)e, o0, o1);
    uint32_t bits = o0 ^ o1;
    float u01 = __uint_as_float((bits >> 9) | 0x3f800000u) - 1.0f;
    float u = fmaxf(u01 + TINY, TINY);          // u01*(1-tiny == 1.0f) + tiny, then max
    float g = -logf(-logf(u));
    float val = logits[e] + g;
    if (val > best) { best = val; argr = r; }   // first-occurrence argmax
  }
  sel[n * BB + b] = argr;
}

// ---------------- K4: word-level co-attention + softmax pooling ----------------
// grid = P*B blocks (p*B + b), 256 threads
__global__ __launch_bounds__(256) void word_coatt(
    const int* __restrict__ uidx, const int* __restrict__ iidx,
    const float* __restrict__ emb,
    const float* __restrict__ wa_w, const float* __restrict__ wa_b,
    const float* __restrict__ wa_M,
    const int* __restrict__ sel, float* __restrict__ x) {
  int bid = blockIdx.x;
  int p = bid / BB, b = bid % BB;
  int ru = sel[(2 * p) * BB + b];
  int rv = sel[(2 * p + 1) * BB + b];
  __shared__ float ur[LL][DD];
  __shared__ float ir[LL][DD];
  __shared__ float uo[LL][DD];   // later overlaid by sw (2500 <= 3200 floats)
  __shared__ float io[LL][DD];
  __shared__ float a2[LL][DD];
  __shared__ float rm[LL], cm[LL];
  int tid = threadIdx.x;
  const int* ui = uidx + ((size_t)b * RR + ru) * LL;
  const int* ii = iidx + ((size_t)b * RR + rv) * LL;
  for (int i = tid; i < LL * DD; i += 256) {
    int l = i / DD, d = i % DD;
    ur[l][d] = emb[(size_t)ui[l] * DD + d];
    ir[l][d] = emb[(size_t)ii[l] * DD + d];
  }
  __syncthreads();
  for (int i = tid; i < LL * DD; i += 256) {
    int l = i / DD, d = i % DD;
    float a = wa_b[d], c = wa_b[d];
    const float* wr_ = wa_w + d * DD;
    for (int e = 0; e < DD; ++e) {
      a += ur[l][e] * wr_[e];
      c += ir[l][e] * wr_[e];
    }
    uo[l][d] = fmaxf(a, 0.f);
    io[l][d] = fmaxf(c, 0.f);
  }
  __syncthreads();
  for (int i = tid; i < LL * DD; i += 256) {
    int l = i / DD, e = i % DD;
    float a = 0.f;
    for (int d2 = 0; d2 < DD; ++d2) a += uo[l][d2] * wa_M[d2 * DD + e];
    a2[l][e] = a;
  }
  __syncthreads();
  float* sw = &uo[0][0];  // reuse uo's LDS for the 50x50 score matrix
  for (int i = tid; i < LL * LL; i += 256) {
    int li = i / LL, lj = i % LL;
    float a = 0.f;
    for (int e = 0; e < DD; ++e) a += a2[li][e] * io[lj][e];
    sw[li * LL + lj] = a;
  }
  __syncthreads();
  if (tid < LL) {
    float a = 0.f;
    for (int j = 0; j < LL; ++j) a += sw[tid * LL + j];
    rm[tid] = a / (float)LL;
  } else if (tid >= 64 && tid < 64 + LL) {
    int j = tid - 64;
    float a = 0.f;
    for (int i2 = 0; i2 < LL; ++i2) a += sw[i2 * LL + j];
    cm[j] = a / (float)LL;
  }
  __syncthreads();
  if (tid == 0) {
    float m = -INFINITY;
    for (int l = 0; l < LL; ++l) m = fmaxf(m, rm[l]);
    float s = 0.f;
    for (int l = 0; l < LL; ++l) { rm[l] = expf(rm[l] - m); s += rm[l]; }
    for (int l = 0; l < LL; ++l) rm[l] /= s;
  } else if (tid == 64) {
    float m = -INFINITY;
    for (int l = 0; l < LL; ++l) m = fmaxf(m, cm[l]);
    float s = 0.f;
    for (int l = 0; l < LL; ++l) { cm[l] = expf(cm[l] - m); s += cm[l]; }
    for (int l = 0; l < LL; ++l) cm[l] /= s;
  }
  __syncthreads();
  // x layout: [u_p0 | u_p1 | i_p0 | i_p1], each 64
  if (tid < DD) {
    float a = 0.f;
    for (int l = 0; l < LL; ++l) a += rm[l] * ur[l][tid];
    x[(size_t)b * IN_DIM + p * DD + tid] = a;
  } else if (tid >= 64 && tid < 128) {
    int d = tid - 64;
    float a = 0.f;
    for (int l = 0; l < LL; ++l) a += cm[l] * ir[l][d];
    x[(size_t)b * IN_DIM + 2 * DD + p * DD + d] = a;
  }
}

// ---------------- K5: FM head ----------------
__global__ __launch_bounds__(256) void fm_head(
    const float* __restrict__ x, const float* __restrict__ fm_v,
    const float* __restrict__ fm_w, const float* __restrict__ fm_b,
    float* __restrict__ out) {
  int b = blockIdx.x * blockDim.x + threadIdx.x;
  if (b >= BB) return;
  const float* xb = x + (size_t)b * IN_DIM;
  float lin = 0.f;
  float i1[KK], i2[KK];
  for (int k = 0; k < KK; ++k) { i1[k] = 0.f; i2[k] = 0.f; }
  for (int j = 0; j < IN_DIM; ++j) {
    float xv = xb[j];
    lin += xv * fm_w[j];
    float x2 = xv * xv;
    const float* vr = fm_v + j * KK;
    for (int k = 0; k < KK; ++k) {
      float v = vr[k];
      i1[k] += xv * v;
      i2[k] += x2 * (v * v);
    }
  }
  float pair = 0.f;
  for (int k = 0; k < KK; ++k) pair += i1[k] * i1[k] - i2[k];
  out[b] = (lin + fm_b[0]) + 0.5f * pair;
}

extern "C" void kernel_launch(void* const* d_in, const int* in_sizes, int n_in,
                              void* d_out, int out_size, void* d_ws, size_t ws_size,
                              hipStream_t stream) {
  (void)in_sizes; (void)n_in; (void)out_size; (void)ws_size;
  const int*   user_reviews = (const int*)d_in[0];
  const int*   item_reviews = (const int*)d_in[1];
  const float* emb  = (const float*)d_in[2];
  const float* gw1  = (const float*)d_in[3];
  const float* gw2  = (const float*)d_in[4];
  const float* gb2  = (const float*)d_in[5];
  const float* gbg  = (const float*)d_in[6];
  const float* ra_w = (const float*)d_in[7];
  const float* ra_b = (const float*)d_in[8];
  const float* ra_M = (const float*)d_in[9];
  const float* wa_w = (const float*)d_in[10];
  const float* wa_b = (const float*)d_in[11];
  const float* wa_M = (const float*)d_in[12];
  const float* fm_v = (const float*)d_in[13];
  const float* fm_w = (const float*)d_in[14];
  const float* fm_b = (const float*)d_in[15];
  float* out = (float*)d_out;

  float* ws = (float*)d_ws;
  float* u_rev = ws;                          // B*R*D
  float* i_rev = u_rev + BB * RR * DD;        // B*R*D
  float* row_logits = i_rev + BB * RR * DD;   // B*R
  float* col_logits = row_logits + BB * RR;   // B*R
  float* x = col_logits + BB * RR;            // B*256
  int* sel = (int*)(x + BB * IN_DIM);         // 4*B ints

  embed_gate<<<dim3(2 * BB * RR), dim3(64), 0, stream>>>(
      user_reviews, item_reviews, emb, gw1, gw2, gb2, gbg, u_rev, i_rev);
  coatt_rev<<<dim3(BB), dim3(256), 0, stream>>>(
      u_rev, i_rev, ra_w, ra_b, ra_M, row_logits, col_logits);
  gumbel_select<<<dim3(4), dim3(512), 0, stream>>>(row_logits, col_logits, sel);
  word_coatt<<<dim3(PP * BB), dim3(256), 0, stream>>>(
      user_reviews, item_reviews, emb, wa_w, wa_b, wa_M, sel, x);
  fm_head<<<dim3(2), dim3(256), 0, stream>>>(x, fm_v, fm_w, fm_b, out);
}

// Round 3
// 256.173 us; speedup vs baseline: 1.1016x; 1.1016x over previous
//
#include <hip/hip_runtime.h>
#include <stdint.h>
#include <math.h>

#define BB 512
#define RR 20
#define LL 50
#define DD 64
#define PP 2
#define KK 10
#define IN_DIM 256   // 2*P*D

// ---------------- threefry2x32 (bit-exact JAX) ----------------
__device__ __forceinline__ uint32_t rotl32(uint32_t v, int d) {
  return (v << d) | (v >> (32 - d));
}

__device__ __forceinline__ void tf2x32(uint32_t k0, uint32_t k1,
                                       uint32_t x0, uint32_t x1,
                                       uint32_t& o0, uint32_t& o1) {
  uint32_t ks0 = k0, ks1 = k1, ks2 = k0 ^ k1 ^ 0x1BD11BDAu;
  x0 += ks0; x1 += ks1;
#define TF_RND(r) { x0 += x1; x1 = rotl32(x1, r); x1 ^= x0; }
  TF_RND(13) TF_RND(15) TF_RND(26) TF_RND(6)
  x0 += ks1; x1 += ks2 + 1u;
  TF_RND(17) TF_RND(29) TF_RND(16) TF_RND(24)
  x0 += ks2; x1 += ks0 + 2u;
  TF_RND(13) TF_RND(15) TF_RND(26) TF_RND(6)
  x0 += ks0; x1 += ks1 + 3u;
  TF_RND(17) TF_RND(29) TF_RND(16) TF_RND(24)
  x0 += ks1; x1 += ks2 + 4u;
  TF_RND(13) TF_RND(15) TF_RND(26) TF_RND(6)
  x0 += ks2; x1 += ks0 + 5u;
#undef TF_RND
  o0 = x0; o1 = x1;
}

__device__ __forceinline__ float wave_sum(float v) {
  for (int off = 32; off; off >>= 1) v += __shfl_xor(v, off, 64);
  return v;
}
__device__ __forceinline__ float wave_max(float v) {
  for (int off = 32; off; off >>= 1) v = fmaxf(v, __shfl_xor(v, off, 64));
  return v;
}

// ---------------- K0: transpose 64x64 weight matrices into d_ws ----------------
__global__ __launch_bounds__(256) void transpose_w(
    const float* __restrict__ w1, const float* __restrict__ w2,
    const float* __restrict__ ra, const float* __restrict__ wa,
    float* __restrict__ w1T, float* __restrict__ w2T,
    float* __restrict__ raT, float* __restrict__ waT) {
  int i = blockIdx.x * 256 + threadIdx.x;
  if (i < DD * DD) {
    int r = i >> 6, c = i & 63;
    w1T[c * DD + r] = w1[i];
    w2T[c * DD + r] = w2[i];
    raT[c * DD + r] = ra[i];
    waT[c * DD + r] = wa[i];
  }
}

// ---------------- K1: embedding sum + gating ----------------
// grid = 2*B*R/4 blocks, 256 threads (4 waves, 1 review per wave)
__global__ __launch_bounds__(256) void embed_gate(
    const int* __restrict__ uidx, const int* __restrict__ iidx,
    const float* __restrict__ emb,
    const float* __restrict__ w1T, const float* __restrict__ w2T,
    const float* __restrict__ b2, const float* __restrict__ bg,
    float* __restrict__ u_rev, float* __restrict__ i_rev) {
  int w = threadIdx.x >> 6, d = threadIdx.x & 63;
  int gid = blockIdx.x * 4 + w;               // 0..20479
  int ui = gid / (BB * RR);
  int t  = gid % (BB * RR);
  const int* idx = (ui ? iidx : uidx) + (size_t)t * LL;
  __shared__ float us[4][DD];
  float s = 0.f;
  // strictly sequential add order (matches reference sum over l)
  for (int l = 0; l < LL; ++l) s += emb[(size_t)idx[l] * DD + d];
  us[w][d] = s;
  __syncthreads();
  float dot1 = 0.f, dot2 = 0.f;
  for (int e = 0; e < DD; ++e) {
    float xv = us[w][e];                       // LDS broadcast
    dot1 += xv * w1T[e * DD + d];              // coalesced, L1-hot
    dot2 += xv * w2T[e * DD + d];
  }
  float sig = 1.f / (1.f + expf(-dot1));
  float val = sig + bg[d] * tanhf(dot2 + b2[d]);
  (ui ? i_rev : u_rev)[(size_t)t * DD + d] = val;
}

// ---------------- K2: review co-attention + gumbel selection (fused) ----------------
// grid = B blocks, 256 threads
__global__ __launch_bounds__(256) void coatt_rev_sel(
    const float* __restrict__ u_rev, const float* __restrict__ i_rev,
    const float* __restrict__ raT, const float* __restrict__ ra_b,
    const float* __restrict__ ra_M, int* __restrict__ sel) {
  int b = blockIdx.x;
  __shared__ float ur[RR * 65], ir[RR * 65], uo[RR * 65], io[RR * 65], au[RR * 65];
  __shared__ float sc[RR * 21];
  __shared__ float rl[RR], cl[RR];
  __shared__ float gval[4][RR];
  int tid = threadIdx.x;
  for (int i = tid; i < RR * DD; i += 256) {
    int r = i >> 6, d = i & 63;
    ur[r * 65 + d] = u_rev[(size_t)b * RR * DD + i];
    ir[r * 65 + d] = i_rev[(size_t)b * RR * DD + i];
  }
  __syncthreads();
  for (int i = tid; i < RR * DD; i += 256) {
    int u = i >> 6, d = i & 63;
    float bb = ra_b[d];
    float a1 = bb, a2 = bb;
    for (int e = 0; e < DD; ++e) {
      float wv = raT[e * DD + d];
      a1 += ur[u * 65 + e] * wv;
      a2 += ir[u * 65 + e] * wv;
    }
    uo[u * 65 + d] = fmaxf(a1, 0.f);
    io[u * 65 + d] = fmaxf(a2, 0.f);
  }
  __syncthreads();
  for (int i = tid; i < RR * DD; i += 256) {
    int u = i >> 6, e = i & 63;
    float a = 0.f;
    for (int d2 = 0; d2 < DD; ++d2) a += uo[u * 65 + d2] * ra_M[d2 * DD + e];
    au[u * 65 + e] = a;
  }
  __syncthreads();
  for (int i = tid; i < RR * RR; i += 256) {
    int u = i / RR, v = i % RR;
    float a = 0.f;
    for (int e = 0; e < DD; ++e) a += au[u * 65 + e] * io[v * 65 + e];
    sc[u * 21 + v] = a;
  }
  __syncthreads();
  if (tid < RR) {
    float m = -INFINITY;
    for (int v = 0; v < RR; ++v) m = fmaxf(m, sc[tid * 21 + v]);
    rl[tid] = m;
  } else if (tid >= 64 && tid < 64 + RR) {
    int v = tid - 64;
    float m = -INFINITY;
    for (int u = 0; u < RR; ++u) m = fmaxf(m, sc[u * 21 + v]);
    cl[v] = m;
  }
  __syncthreads();
  if (tid < 4 * RR) {
    int n = tid / RR, r = tid % RR;
    uint32_t k0, k1, o0, o1;
    tf2x32(0u, 42u, 0u, (uint32_t)n, k0, k1);       // fold_in(key(42), n)
    int e = b * RR + r;
    tf2x32(k0, k1, 0u, (uint32_t)e, o0, o1);        // partitionable threefry
    uint32_t bits = o0 ^ o1;
    float u01 = __uint_as_float((bits >> 9) | 0x3f800000u) - 1.0f;
    const float TINY = 1.1754943508222875e-38f;
    float u = fmaxf(u01 + TINY, TINY);
    float g = -logf(-logf(u));
    gval[n][r] = ((n & 1) ? cl[r] : rl[r]) + g;
  }
  __syncthreads();
  if (tid < 4) {
    float best = -INFINITY; int arg = 0;
    for (int r = 0; r < RR; ++r) {                   // serial: first-max tie-break
      float v = gval[tid][r];
      if (v > best) { best = v; arg = r; }
    }
    sel[tid * BB + b] = arg;
  }
}

// ---------------- K3: word-level co-attention + softmax pooling ----------------
// grid = P*B blocks, 256 threads. LDS ~52 KB -> 3 blocks/CU.
__global__ __launch_bounds__(256) void word_coatt(
    const int* __restrict__ uidx, const int* __restrict__ iidx,
    const float* __restrict__ emb,
    const float* __restrict__ waT, const float* __restrict__ wa_b,
    const float* __restrict__ wa_M,
    const int* __restrict__ sel, float* __restrict__ x) {
  int bid = blockIdx.x;
  int p = bid >> 9, b = bid & (BB - 1);
  int ru = sel[(2 * p) * BB + b];
  int rv = sel[(2 * p + 1) * BB + b];
  __shared__ float ur[LL * 65], ir[LL * 65], S1[LL * 65];  // S1: io then uo
  __shared__ float Z[DD * 51];                              // Z = M @ io^T
  __shared__ float rm[LL], cm[LL];
  int tid = threadIdx.x;
  int w = tid >> 6, lane = tid & 63;
  const int* ui = uidx + ((size_t)b * RR + ru) * LL;
  const int* ii = iidx + ((size_t)b * RR + rv) * LL;
  for (int i = tid; i < LL * DD; i += 256) {
    int l = i >> 6, d = i & 63;
    ur[l * 65 + d] = emb[(size_t)ui[l] * DD + d];
    ir[l * 65 + d] = emb[(size_t)ii[l] * DD + d];
  }
  __syncthreads();
  // io = relu(ir @ W^T + b) -> S1
  for (int i = tid; i < LL * DD; i += 256) {
    int l = i >> 6, d = i & 63;
    float a = wa_b[d];
    for (int e = 0; e < DD; ++e) a += ir[l * 65 + e] * waT[e * DD + d];
    S1[l * 65 + d] = fmaxf(a, 0.f);
  }
  __syncthreads();
  // Z[d2][lj] = sum_e M[d2][e] * io[lj][e]
  for (int i = tid; i < DD * LL; i += 256) {
    int d2 = i / LL, lj = i % LL;
    float a = 0.f;
    for (int e = 0; e < DD; ++e) a += wa_M[d2 * DD + e] * S1[lj * 65 + e];
    Z[d2 * 51 + lj] = a;
  }
  __syncthreads();
  // uo = relu(ur @ W^T + b) -> S1 (overwrites io; io fully consumed by Z)
  for (int i = tid; i < LL * DD; i += 256) {
    int l = i >> 6, d = i & 63;
    float a = wa_b[d];
    for (int e = 0; e < DD; ++e) a += ur[l * 65 + e] * waT[e * DD + d];
    S1[l * 65 + d] = fmaxf(a, 0.f);
  }
  __syncthreads();
  // row means: rm[li] = mean_lj sum_d2 uo[li][d2] * Z[d2][lj]
  for (int li = w; li < LL; li += 4) {
    float s = 0.f;
    if (lane < LL) {
      for (int d2 = 0; d2 < DD; ++d2) s += S1[li * 65 + d2] * Z[d2 * 51 + lane];
    }
    float tot = wave_sum(s);
    if (lane == 0) rm[li] = tot / 50.f;
  }
  // col means
  for (int lj = w; lj < LL; lj += 4) {
    float s = 0.f;
    if (lane < LL) {
      for (int d2 = 0; d2 < DD; ++d2) s += S1[lane * 65 + d2] * Z[d2 * 51 + lj];
    }
    float tot = wave_sum(s);
    if (lane == 0) cm[lj] = tot / 50.f;
  }
  __syncthreads();
  // wave-parallel softmax
  if (w == 0) {
    float v = (lane < LL) ? rm[lane] : -INFINITY;
    float m = wave_max(v);
    float ex = (lane < LL) ? expf(rm[lane] - m) : 0.f;
    float sm = wave_sum(ex);
    if (lane < LL) rm[lane] = ex / sm;
  } else if (w == 1) {
    float v = (lane < LL) ? cm[lane] : -INFINITY;
    float m = wave_max(v);
    float ex = (lane < LL) ? expf(cm[lane] - m) : 0.f;
    float sm = wave_sum(ex);
    if (lane < LL) cm[lane] = ex / sm;
  }
  __syncthreads();
  // pooling; x layout: [u_p0 | u_p1 | i_p0 | i_p1]
  if (w == 0) {
    float a = 0.f;
    for (int l = 0; l < LL; ++l) a += rm[l] * ur[l * 65 + lane];
    x[(size_t)b * IN_DIM + p * DD + lane] = a;
  } else if (w == 1) {
    float a = 0.f;
    for (int l = 0; l < LL; ++l) a += cm[l] * ir[l * 65 + lane];
    x[(size_t)b * IN_DIM + 2 * DD + p * DD + lane] = a;
  }
}

// ---------------- K4: FM head ----------------
__global__ __launch_bounds__(256) void fm_head(
    const float* __restrict__ x, const float* __restrict__ fm_v,
    const float* __restrict__ fm_w, const float* __restrict__ fm_b,
    float* __restrict__ out) {
  int b = blockIdx.x * blockDim.x + threadIdx.x;
  if (b >= BB) return;
  const float* xb = x + (size_t)b * IN_DIM;
  float lin = 0.f;
  float i1[KK], i2[KK];
  for (int k = 0; k < KK; ++k) { i1[k] = 0.f; i2[k] = 0.f; }
  for (int j = 0; j < IN_DIM; ++j) {
    float xv = xb[j];
    lin += xv * fm_w[j];
    float x2 = xv * xv;
    const float* vr = fm_v + j * KK;
    for (int k = 0; k < KK; ++k) {
      float v = vr[k];
      i1[k] += xv * v;
      i2[k] += x2 * (v * v);
    }
  }
  float pair = 0.f;
  for (int k = 0; k < KK; ++k) pair += i1[k] * i1[k] - i2[k];
  out[b] = (lin + fm_b[0]) + 0.5f * pair;
}

extern "C" void kernel_launch(void* const* d_in, const int* in_sizes, int n_in,
                              void* d_out, int out_size, void* d_ws, size_t ws_size,
                              hipStream_t stream) {
  (void)in_sizes; (void)n_in; (void)out_size; (void)ws_size;
  const int*   user_reviews = (const int*)d_in[0];
  const int*   item_reviews = (const int*)d_in[1];
  const float* emb  = (const float*)d_in[2];
  const float* gw1  = (const float*)d_in[3];
  const float* gw2  = (const float*)d_in[4];
  const float* gb2  = (const float*)d_in[5];
  const float* gbg  = (const float*)d_in[6];
  const float* ra_w = (const float*)d_in[7];
  const float* ra_b = (const float*)d_in[8];
  const float* ra_M = (const float*)d_in[9];
  const float* wa_w = (const float*)d_in[10];
  const float* wa_b = (const float*)d_in[11];
  const float* wa_M = (const float*)d_in[12];
  const float* fm_v = (const float*)d_in[13];
  const float* fm_w = (const float*)d_in[14];
  const float* fm_b = (const float*)d_in[15];
  float* out = (float*)d_out;

  float* ws = (float*)d_ws;
  float* u_rev = ws;                        // B*R*D
  float* i_rev = u_rev + BB * RR * DD;      // B*R*D
  float* x     = i_rev + BB * RR * DD;      // B*256
  float* w1T   = x + BB * IN_DIM;           // 4096
  float* w2T   = w1T + DD * DD;
  float* raT   = w2T + DD * DD;
  float* waT   = raT + DD * DD;
  int*   sel   = (int*)(waT + DD * DD);     // 4*B ints

  transpose_w<<<dim3(16), dim3(256), 0, stream>>>(gw1, gw2, ra_w, wa_w,
                                                  w1T, w2T, raT, waT);
  embed_gate<<<dim3(2 * BB * RR / 4), dim3(256), 0, stream>>>(
      user_reviews, item_reviews, emb, w1T, w2T, gb2, gbg, u_rev, i_rev);
  coatt_rev_sel<<<dim3(BB), dim3(256), 0, stream>>>(
      u_rev, i_rev, raT, ra_b, ra_M, sel);
  word_coatt<<<dim3(PP * BB), dim3(256), 0, stream>>>(
      user_reviews, item_reviews, emb, waT, wa_b, wa_M, sel, x);
  fm_head<<<dim3(2), dim3(256), 0, stream>>>(x, fm_v, fm_w, fm_b, out);
}

// Round 4
// 159.255 us; speedup vs baseline: 1.7720x; 1.6086x over previous
//
#include <hip/hip_runtime.h>
#include <stdint.h>
#include <math.h>

#define BB 512
#define RR 20
#define LL 50
#define DD 64
#define PP 2
#define KK 10
#define IN_DIM 256   // 2*P*D
#define VV 50000

// ---------------- threefry2x32 (bit-exact JAX) ----------------
__device__ __forceinline__ uint32_t rotl32(uint32_t v, int d) {
  return (v << d) | (v >> (32 - d));
}

__device__ __forceinline__ void tf2x32(uint32_t k0, uint32_t k1,
                                       uint32_t x0, uint32_t x1,
                                       uint32_t& o0, uint32_t& o1) {
  uint32_t ks0 = k0, ks1 = k1, ks2 = k0 ^ k1 ^ 0x1BD11BDAu;
  x0 += ks0; x1 += ks1;
#define TF_RND(r) { x0 += x1; x1 = rotl32(x1, r); x1 ^= x0; }
  TF_RND(13) TF_RND(15) TF_RND(26) TF_RND(6)
  x0 += ks1; x1 += ks2 + 1u;
  TF_RND(17) TF_RND(29) TF_RND(16) TF_RND(24)
  x0 += ks2; x1 += ks0 + 2u;
  TF_RND(13) TF_RND(15) TF_RND(26) TF_RND(6)
  x0 += ks0; x1 += ks1 + 3u;
  TF_RND(17) TF_RND(29) TF_RND(16) TF_RND(24)
  x0 += ks1; x1 += ks2 + 4u;
  TF_RND(13) TF_RND(15) TF_RND(26) TF_RND(6)
  x0 += ks2; x1 += ks0 + 5u;
#undef TF_RND
  o0 = x0; o1 = x1;
}

__device__ __forceinline__ float wave_sum(float v) {
  for (int off = 32; off; off >>= 1) v += __shfl_xor(v, off, 64);
  return v;
}
__device__ __forceinline__ float wave_max(float v) {
  for (int off = 32; off; off >>= 1) v = fmaxf(v, __shfl_xor(v, off, 64));
  return v;
}

// ---------------- K0: transpose the 64x64 weight matrices ----------------
__global__ __launch_bounds__(256) void transpose_w(
    const float* __restrict__ w1, const float* __restrict__ w2,
    const float* __restrict__ ra, const float* __restrict__ wa,
    const float* __restrict__ ma,
    float* __restrict__ w1T, float* __restrict__ w2T,
    float* __restrict__ raT, float* __restrict__ waT,
    float* __restrict__ maT) {
  int i = blockIdx.x * 256 + threadIdx.x;
  if (i < DD * DD) {
    int r = i >> 6, c = i & 63;
    w1T[c * DD + r] = w1[i];
    w2T[c * DD + r] = w2[i];
    raT[c * DD + r] = ra[i];
    waT[c * DD + r] = wa[i];
    maT[c * DD + r] = ma[i];
  }
}

// ---------------- K0b: per-vocab tables E1 = relu(emb@W^T+b), E2 = M@E1 ----------------
// grid = V/4 blocks, 256 threads (wave per word)
__global__ __launch_bounds__(256) void build_tables(
    const float* __restrict__ emb, const float* __restrict__ waT,
    const float* __restrict__ wa_b, const float* __restrict__ maT,
    float* __restrict__ E1, float* __restrict__ E2) {
  int wid = threadIdx.x >> 6, d = threadIdx.x & 63;
  int v = blockIdx.x * 4 + wid;          // V = 50000 = 12500*4, always valid
  __shared__ float ev[4][65], rel[4][65];
  ev[wid][d] = emb[(size_t)v * DD + d];
  __syncthreads();
  float a = wa_b[d];
  for (int e = 0; e < DD; ++e) a += ev[wid][e] * waT[e * DD + d];
  float r = fmaxf(a, 0.f);
  rel[wid][d] = r;
  E1[(size_t)v * DD + d] = r;
  __syncthreads();
  float z = 0.f;
  for (int e = 0; e < DD; ++e) z += rel[wid][e] * maT[e * DD + d];  // = M[d][e]
  E2[(size_t)v * DD + d] = z;
}

// ---------------- K1: embedding sum + gating ----------------
// grid = 1280 blocks (16 reviews each: blocks 0..639 user, 640..1279 item)
// wave handles 4 reviews via float4 lanes (16 lanes per review)
__global__ __launch_bounds__(256) void embed_gate(
    const int* __restrict__ uidx, const int* __restrict__ iidx,
    const float* __restrict__ emb,
    const float* __restrict__ w1T, const float* __restrict__ w2T,
    const float* __restrict__ b2, const float* __restrict__ bg,
    float* __restrict__ u_rev, float* __restrict__ i_rev) {
  __shared__ int idxs[16 * LL];
  __shared__ float us[16][68];
  int tid = threadIdx.x;
  int isItem = (blockIdx.x >= 640);
  const int* src = isItem ? (iidx + (size_t)(blockIdx.x - 640) * 16 * LL)
                          : (uidx + (size_t)blockIdx.x * 16 * LL);
  for (int i = tid; i < 16 * LL; i += 256) idxs[i] = src[i];
  __syncthreads();
  int w = tid >> 6, lane = tid & 63;
  int revl = w * 4 + (lane >> 4);
  int q = lane & 15;
  const int* myidx = idxs + revl * LL;
  float4 acc = {0.f, 0.f, 0.f, 0.f};
  // per-component accumulation order identical to reference (l sequential)
  for (int l = 0; l < LL; ++l) {
    int v = myidx[l];
    float4 e4 = *reinterpret_cast<const float4*>(&emb[(size_t)v * DD + q * 4]);
    acc.x += e4.x; acc.y += e4.y; acc.z += e4.z; acc.w += e4.w;
  }
  *reinterpret_cast<float4*>(&us[revl][q * 4]) = acc;
  __syncthreads();
  int d = lane;
  for (int rr = 0; rr < 4; ++rr) {
    int rv = w * 4 + rr;
    float dot1 = 0.f, dot2 = 0.f;
    for (int e = 0; e < DD; ++e) {
      float xv = us[rv][e];                  // LDS broadcast
      dot1 += xv * w1T[e * DD + d];          // coalesced, L1-hot
      dot2 += xv * w2T[e * DD + d];
    }
    float sig = 1.f / (1.f + expf(-dot1));
    float val = sig + bg[d] * tanhf(dot2 + b2[d]);
    int gid = blockIdx.x * 16 + rv;
    int t = gid % (BB * RR);
    (gid >= BB * RR ? i_rev : u_rev)[(size_t)t * DD + d] = val;
  }
}

// ---------------- K2: review co-attention + gumbel selection (BIT-IDENTICAL to R3) ----------------
__global__ __launch_bounds__(256) void coatt_rev_sel(
    const float* __restrict__ u_rev, const float* __restrict__ i_rev,
    const float* __restrict__ raT, const float* __restrict__ ra_b,
    const float* __restrict__ ra_M, int* __restrict__ sel) {
  int b = blockIdx.x;
  __shared__ float ur[RR * 65], ir[RR * 65], uo[RR * 65], io[RR * 65], au[RR * 65];
  __shared__ float sc[RR * 21];
  __shared__ float rl[RR], cl[RR];
  __shared__ float gval[4][RR];
  int tid = threadIdx.x;
  for (int i = tid; i < RR * DD; i += 256) {
    int r = i >> 6, d = i & 63;
    ur[r * 65 + d] = u_rev[(size_t)b * RR * DD + i];
    ir[r * 65 + d] = i_rev[(size_t)b * RR * DD + i];
  }
  __syncthreads();
  for (int i = tid; i < RR * DD; i += 256) {
    int u = i >> 6, d = i & 63;
    float bb = ra_b[d];
    float a1 = bb, a2 = bb;
    for (int e = 0; e < DD; ++e) {
      float wv = raT[e * DD + d];
      a1 += ur[u * 65 + e] * wv;
      a2 += ir[u * 65 + e] * wv;
    }
    uo[u * 65 + d] = fmaxf(a1, 0.f);
    io[u * 65 + d] = fmaxf(a2, 0.f);
  }
  __syncthreads();
  for (int i = tid; i < RR * DD; i += 256) {
    int u = i >> 6, e = i & 63;
    float a = 0.f;
    for (int d2 = 0; d2 < DD; ++d2) a += uo[u * 65 + d2] * ra_M[d2 * DD + e];
    au[u * 65 + e] = a;
  }
  __syncthreads();
  for (int i = tid; i < RR * RR; i += 256) {
    int u = i / RR, v = i % RR;
    float a = 0.f;
    for (int e = 0; e < DD; ++e) a += au[u * 65 + e] * io[v * 65 + e];
    sc[u * 21 + v] = a;
  }
  __syncthreads();
  if (tid < RR) {
    float m = -INFINITY;
    for (int v = 0; v < RR; ++v) m = fmaxf(m, sc[tid * 21 + v]);
    rl[tid] = m;
  } else if (tid >= 64 && tid < 64 + RR) {
    int v = tid - 64;
    float m = -INFINITY;
    for (int u = 0; u < RR; ++u) m = fmaxf(m, sc[u * 21 + v]);
    cl[v] = m;
  }
  __syncthreads();
  if (tid < 4 * RR) {
    int n = tid / RR, r = tid % RR;
    uint32_t k0, k1, o0, o1;
    tf2x32(0u, 42u, 0u, (uint32_t)n, k0, k1);       // fold_in(key(42), n)
    int e = b * RR + r;
    tf2x32(k0, k1, 0u, (uint32_t)e, o0, o1);        // partitionable threefry
    uint32_t bits = o0 ^ o1;
    float u01 = __uint_as_float((bits >> 9) | 0x3f800000u) - 1.0f;
    const float TINY = 1.1754943508222875e-38f;
    float u = fmaxf(u01 + TINY, TINY);
    float g = -logf(-logf(u));
    gval[n][r] = ((n & 1) ? cl[r] : rl[r]) + g;
  }
  __syncthreads();
  if (tid < 4) {
    float best = -INFINITY; int arg = 0;
    for (int r = 0; r < RR; ++r) {                   // serial: first-max tie-break
      float v = gval[tid][r];
      if (v > best) { best = v; arg = r; }
    }
    sel[tid * BB + b] = arg;
  }
}

// ---------------- K3: word-level attention via tables (mean distributes over dot) ----------------
// grid = P*B blocks, 256 threads. LDS ~27 KB.
__global__ __launch_bounds__(256) void word_coatt(
    const int* __restrict__ uidx, const int* __restrict__ iidx,
    const float* __restrict__ emb,
    const float* __restrict__ E1, const float* __restrict__ E2,
    const int* __restrict__ sel, float* __restrict__ x) {
  int bid = blockIdx.x;
  int p = bid >> 9, b = bid & (BB - 1);
  int ru = sel[(2 * p) * BB + b];
  int rv = sel[(2 * p + 1) * BB + b];
  __shared__ int uw[LL], iw[LL];
  __shared__ float E1u[LL * 65], E2i[LL * 65];
  __shared__ float ubar[DD], zbar[DD];
  __shared__ float rm[LL], cm[LL];
  int tid = threadIdx.x;
  if (tid < LL) uw[tid] = uidx[((size_t)b * RR + ru) * LL + tid];
  else if (tid >= 64 && tid < 64 + LL) iw[tid - 64] = iidx[((size_t)b * RR + rv) * LL + (tid - 64)];
  __syncthreads();
  for (int i = tid; i < LL * DD; i += 256) {
    int l = i >> 6, d = i & 63;
    E1u[l * 65 + d] = E1[(size_t)uw[l] * DD + d];
    E2i[l * 65 + d] = E2[(size_t)iw[l] * DD + d];
  }
  __syncthreads();
  if (tid < DD) {                 // ubar = mean of user E1 rows
    float s = 0.f;
    for (int l = 0; l < LL; ++l) s += E1u[l * 65 + tid];
    ubar[tid] = s / 50.f;
  } else if (tid < 128) {         // zbar = mean of item E2 rows
    int d = tid - 64;
    float s = 0.f;
    for (int l = 0; l < LL; ++l) s += E2i[l * 65 + d];
    zbar[d] = s / 50.f;
  }
  __syncthreads();
  if (tid < LL) {                 // rm[li] = E1u[li] . zbar
    float a = 0.f;
    for (int e = 0; e < DD; ++e) a += E1u[tid * 65 + e] * zbar[e];
    rm[tid] = a;
  } else if (tid >= 64 && tid < 64 + LL) {  // cm[lj] = ubar . E2i[lj]
    int lj = tid - 64;
    float a = 0.f;
    for (int e = 0; e < DD; ++e) a += ubar[e] * E2i[lj * 65 + e];
    cm[lj] = a;
  }
  __syncthreads();
  int w = tid >> 6, lane = tid & 63;
  if (w == 0) {
    float v = (lane < LL) ? rm[lane] : -INFINITY;
    float m = wave_max(v);
    float ex = (lane < LL) ? expf(rm[lane] - m) : 0.f;
    float sm = wave_sum(ex);
    if (lane < LL) rm[lane] = ex / sm;
  } else if (w == 1) {
    float v = (lane < LL) ? cm[lane] : -INFINITY;
    float m = wave_max(v);
    float ex = (lane < LL) ? expf(cm[lane] - m) : 0.f;
    float sm = wave_sum(ex);
    if (lane < LL) cm[lane] = ex / sm;
  }
  __syncthreads();
  // pooling from emb directly (L2-hot); x layout: [u_p0 | u_p1 | i_p0 | i_p1]
  if (w == 0) {
    float a = 0.f;
    for (int l = 0; l < LL; ++l) a += rm[l] * emb[(size_t)uw[l] * DD + lane];
    x[(size_t)b * IN_DIM + p * DD + lane] = a;
  } else if (w == 1) {
    float a = 0.f;
    for (int l = 0; l < LL; ++l) a += cm[l] * emb[(size_t)iw[l] * DD + lane];
    x[(size_t)b * IN_DIM + 2 * DD + p * DD + lane] = a;
  }
}

// ---------------- K4: FM head ----------------
__global__ __launch_bounds__(256) void fm_head(
    const float* __restrict__ x, const float* __restrict__ fm_v,
    const float* __restrict__ fm_w, const float* __restrict__ fm_b,
    float* __restrict__ out) {
  int b = blockIdx.x * blockDim.x + threadIdx.x;
  if (b >= BB) return;
  const float* xb = x + (size_t)b * IN_DIM;
  float lin = 0.f;
  float i1[KK], i2[KK];
  for (int k = 0; k < KK; ++k) { i1[k] = 0.f; i2[k] = 0.f; }
  for (int j = 0; j < IN_DIM; ++j) {
    float xv = xb[j];
    lin += xv * fm_w[j];
    float x2 = xv * xv;
    const float* vr = fm_v + j * KK;
    for (int k = 0; k < KK; ++k) {
      float v = vr[k];
      i1[k] += xv * v;
      i2[k] += x2 * (v * v);
    }
  }
  float pair = 0.f;
  for (int k = 0; k < KK; ++k) pair += i1[k] * i1[k] - i2[k];
  out[b] = (lin + fm_b[0]) + 0.5f * pair;
}

extern "C" void kernel_launch(void* const* d_in, const int* in_sizes, int n_in,
                              void* d_out, int out_size, void* d_ws, size_t ws_size,
                              hipStream_t stream) {
  (void)in_sizes; (void)n_in; (void)out_size; (void)ws_size;
  const int*   user_reviews = (const int*)d_in[0];
  const int*   item_reviews = (const int*)d_in[1];
  const float* emb  = (const float*)d_in[2];
  const float* gw1  = (const float*)d_in[3];
  const float* gw2  = (const float*)d_in[4];
  const float* gb2  = (const float*)d_in[5];
  const float* gbg  = (const float*)d_in[6];
  const float* ra_w = (const float*)d_in[7];
  const float* ra_b = (const float*)d_in[8];
  const float* ra_M = (const float*)d_in[9];
  const float* wa_w = (const float*)d_in[10];
  const float* wa_b = (const float*)d_in[11];
  const float* wa_M = (const float*)d_in[12];
  const float* fm_v = (const float*)d_in[13];
  const float* fm_w = (const float*)d_in[14];
  const float* fm_b = (const float*)d_in[15];
  float* out = (float*)d_out;

  float* ws = (float*)d_ws;
  float* u_rev = ws;                        // B*R*D = 655360
  float* i_rev = u_rev + BB * RR * DD;      // 655360
  float* x     = i_rev + BB * RR * DD;      // B*256 = 131072
  float* w1T   = x + BB * IN_DIM;           // 4096 each
  float* w2T   = w1T + DD * DD;
  float* raT   = w2T + DD * DD;
  float* waT   = raT + DD * DD;
  float* maT   = waT + DD * DD;
  float* E1    = maT + DD * DD;             // V*D = 3.2M
  float* E2    = E1 + (size_t)VV * DD;      // V*D = 3.2M
  int*   sel   = (int*)(E2 + (size_t)VV * DD);  // 4*B ints

  transpose_w<<<dim3(16), dim3(256), 0, stream>>>(gw1, gw2, ra_w, wa_w, wa_M,
                                                  w1T, w2T, raT, waT, maT);
  build_tables<<<dim3(VV / 4), dim3(256), 0, stream>>>(emb, waT, wa_b, maT, E1, E2);
  embed_gate<<<dim3(1280), dim3(256), 0, stream>>>(
      user_reviews, item_reviews, emb, w1T, w2T, gb2, gbg, u_rev, i_rev);
  coatt_rev_sel<<<dim3(BB), dim3(256), 0, stream>>>(
      u_rev, i_rev, raT, ra_b, ra_M, sel);
  word_coatt<<<dim3(PP * BB), dim3(256), 0, stream>>>(
      user_reviews, item_reviews, emb, E1, E2, sel, x);
  fm_head<<<dim3(2), dim3(256), 0, stream>>>(x, fm_v, fm_w, fm_b, out);
}

// Round 5
// 133.054 us; speedup vs baseline: 2.1209x; 1.1969x over previous
//
#include <hip/hip_runtime.h>
#include <stdint.h>
#include <math.h>

#define BB 512
#define RR 20
#define LL 50
#define DD 64
#define PP 2
#define KK 10
#define IN_DIM 256   // 2*P*D
#define VV 50000

// ---------------- threefry2x32 (bit-exact JAX) ----------------
__device__ __forceinline__ uint32_t rotl32(uint32_t v, int d) {
  return (v << d) | (v >> (32 - d));
}

__device__ __forceinline__ void tf2x32(uint32_t k0, uint32_t k1,
                                       uint32_t x0, uint32_t x1,
                                       uint32_t& o0, uint32_t& o1) {
  uint32_t ks0 = k0, ks1 = k1, ks2 = k0 ^ k1 ^ 0x1BD11BDAu;
  x0 += ks0; x1 += ks1;
#define TF_RND(r) { x0 += x1; x1 = rotl32(x1, r); x1 ^= x0; }
  TF_RND(13) TF_RND(15) TF_RND(26) TF_RND(6)
  x0 += ks1; x1 += ks2 + 1u;
  TF_RND(17) TF_RND(29) TF_RND(16) TF_RND(24)
  x0 += ks2; x1 += ks0 + 2u;
  TF_RND(13) TF_RND(15) TF_RND(26) TF_RND(6)
  x0 += ks0; x1 += ks1 + 3u;
  TF_RND(17) TF_RND(29) TF_RND(16) TF_RND(24)
  x0 += ks1; x1 += ks2 + 4u;
  TF_RND(13) TF_RND(15) TF_RND(26) TF_RND(6)
  x0 += ks2; x1 += ks0 + 5u;
#undef TF_RND
  o0 = x0; o1 = x1;
}

__device__ __forceinline__ float wave_sum(float v) {
  for (int off = 32; off; off >>= 1) v += __shfl_xor(v, off, 64);
  return v;
}
__device__ __forceinline__ float wave_max(float v) {
  for (int off = 32; off; off >>= 1) v = fmaxf(v, __shfl_xor(v, off, 64));
  return v;
}

// ---------------- K0: transpose the 64x64 weight matrices ----------------
__global__ __launch_bounds__(256) void transpose_w(
    const float* __restrict__ w1, const float* __restrict__ w2,
    const float* __restrict__ ra, const float* __restrict__ wa,
    const float* __restrict__ ma,
    float* __restrict__ w1T, float* __restrict__ w2T,
    float* __restrict__ raT, float* __restrict__ waT,
    float* __restrict__ maT) {
  int i = blockIdx.x * 256 + threadIdx.x;
  if (i < DD * DD) {
    int r = i >> 6, c = i & 63;
    w1T[c * DD + r] = w1[i];
    w2T[c * DD + r] = w2[i];
    raT[c * DD + r] = ra[i];
    waT[c * DD + r] = wa[i];
    maT[c * DD + r] = ma[i];
  }
}

// ---------------- K0b: per-vocab tables E1 = relu(emb@W^T+b), E2 = M@E1 ----------------
// grid = V/16 blocks, 256 threads. 16 lanes per word, float4 outputs per lane.
__global__ __launch_bounds__(256) void build_tables(
    const float* __restrict__ emb, const float* __restrict__ waT,
    const float* __restrict__ wa_b, const float* __restrict__ maT,
    float* __restrict__ E1, float* __restrict__ E2) {
  int tid = threadIdx.x;
  int w = tid >> 6, lane = tid & 63;
  int grp = lane >> 4, q = lane & 15;
  int wl = w * 4 + grp;                        // word slot in block: 0..15
  int v = blockIdx.x * 16 + wl;                // V = 50000 = 3125*16
  __shared__ float ev[16][68];
  __shared__ float rel[16][68];
  float4 e4 = *reinterpret_cast<const float4*>(&emb[(size_t)v * DD + q * 4]);
  *reinterpret_cast<float4*>(&ev[wl][q * 4]) = e4;
  __syncthreads();
  float4 acc = *reinterpret_cast<const float4*>(&wa_b[q * 4]);
  for (int e = 0; e < DD; ++e) {
    float xv = ev[wl][e];                      // LDS broadcast per 16-lane group
    float4 wv = *reinterpret_cast<const float4*>(&waT[e * DD + q * 4]);
    acc.x += xv * wv.x; acc.y += xv * wv.y; acc.z += xv * wv.z; acc.w += xv * wv.w;
  }
  acc.x = fmaxf(acc.x, 0.f); acc.y = fmaxf(acc.y, 0.f);
  acc.z = fmaxf(acc.z, 0.f); acc.w = fmaxf(acc.w, 0.f);
  *reinterpret_cast<float4*>(&rel[wl][q * 4]) = acc;
  *reinterpret_cast<float4*>(&E1[(size_t)v * DD + q * 4]) = acc;
  __syncthreads();
  float4 z = {0.f, 0.f, 0.f, 0.f};
  for (int e = 0; e < DD; ++e) {
    float xv = rel[wl][e];
    float4 mv = *reinterpret_cast<const float4*>(&maT[e * DD + q * 4]);
    z.x += xv * mv.x; z.y += xv * mv.y; z.z += xv * mv.z; z.w += xv * mv.w;
  }
  *reinterpret_cast<float4*>(&E2[(size_t)v * DD + q * 4]) = z;
}

// ---------------- K1: embedding sum + gating ----------------
// grid = 1280 blocks (16 reviews each: blocks 0..639 user, 640..1279 item)
// 16 lanes per review, float4; gating dot keeps e-sequential fmac chain per
// output (bit-identical to prior rounds -> selection-safe).
__global__ __launch_bounds__(256) void embed_gate(
    const int* __restrict__ uidx, const int* __restrict__ iidx,
    const float* __restrict__ emb,
    const float* __restrict__ w1T, const float* __restrict__ w2T,
    const float* __restrict__ b2, const float* __restrict__ bg,
    float* __restrict__ u_rev, float* __restrict__ i_rev) {
  __shared__ int idxs[16 * LL];
  __shared__ float us[16][68];
  int tid = threadIdx.x;
  int isItem = (blockIdx.x >= 640);
  const int* src = isItem ? (iidx + (size_t)(blockIdx.x - 640) * 16 * LL)
                          : (uidx + (size_t)blockIdx.x * 16 * LL);
  for (int i = tid; i < 16 * LL; i += 256) idxs[i] = src[i];
  __syncthreads();
  int w = tid >> 6, lane = tid & 63;
  int grp = lane >> 4, q = lane & 15;
  int revl = w * 4 + grp;
  const int* myidx = idxs + revl * LL;
  float4 acc = {0.f, 0.f, 0.f, 0.f};
  for (int l = 0; l < LL; ++l) {               // l-sequential (matches reference)
    int v = myidx[l];
    float4 e4 = *reinterpret_cast<const float4*>(&emb[(size_t)v * DD + q * 4]);
    acc.x += e4.x; acc.y += e4.y; acc.z += e4.z; acc.w += e4.w;
  }
  *reinterpret_cast<float4*>(&us[revl][q * 4]) = acc;
  __syncthreads();
  float4 d1 = {0.f, 0.f, 0.f, 0.f}, d2 = {0.f, 0.f, 0.f, 0.f};
  for (int e = 0; e < DD; ++e) {
    float xv = us[revl][e];                    // LDS broadcast
    float4 w1v = *reinterpret_cast<const float4*>(&w1T[e * DD + q * 4]);
    float4 w2v = *reinterpret_cast<const float4*>(&w2T[e * DD + q * 4]);
    d1.x += xv * w1v.x; d1.y += xv * w1v.y; d1.z += xv * w1v.z; d1.w += xv * w1v.w;
    d2.x += xv * w2v.x; d2.y += xv * w2v.y; d2.z += xv * w2v.z; d2.w += xv * w2v.w;
  }
  float4 b2v = *reinterpret_cast<const float4*>(&b2[q * 4]);
  float4 bgv = *reinterpret_cast<const float4*>(&bg[q * 4]);
  float4 val;
  val.x = 1.f / (1.f + expf(-d1.x)) + bgv.x * tanhf(d2.x + b2v.x);
  val.y = 1.f / (1.f + expf(-d1.y)) + bgv.y * tanhf(d2.y + b2v.y);
  val.z = 1.f / (1.f + expf(-d1.z)) + bgv.z * tanhf(d2.z + b2v.z);
  val.w = 1.f / (1.f + expf(-d1.w)) + bgv.w * tanhf(d2.w + b2v.w);
  int gid = blockIdx.x * 16 + revl;
  int t = gid % (BB * RR);
  float* dst = (gid >= BB * RR) ? i_rev : u_rev;
  *reinterpret_cast<float4*>(&dst[(size_t)t * DD + q * 4]) = val;
}

// ---------------- K2: review co-attention + gumbel selection (BIT-IDENTICAL, untouched) ----------------
__global__ __launch_bounds__(256) void coatt_rev_sel(
    const float* __restrict__ u_rev, const float* __restrict__ i_rev,
    const float* __restrict__ raT, const float* __restrict__ ra_b,
    const float* __restrict__ ra_M, int* __restrict__ sel) {
  int b = blockIdx.x;
  __shared__ float ur[RR * 65], ir[RR * 65], uo[RR * 65], io[RR * 65], au[RR * 65];
  __shared__ float sc[RR * 21];
  __shared__ float rl[RR], cl[RR];
  __shared__ float gval[4][RR];
  int tid = threadIdx.x;
  for (int i = tid; i < RR * DD; i += 256) {
    int r = i >> 6, d = i & 63;
    ur[r * 65 + d] = u_rev[(size_t)b * RR * DD + i];
    ir[r * 65 + d] = i_rev[(size_t)b * RR * DD + i];
  }
  __syncthreads();
  for (int i = tid; i < RR * DD; i += 256) {
    int u = i >> 6, d = i & 63;
    float bb = ra_b[d];
    float a1 = bb, a2 = bb;
    for (int e = 0; e < DD; ++e) {
      float wv = raT[e * DD + d];
      a1 += ur[u * 65 + e] * wv;
      a2 += ir[u * 65 + e] * wv;
    }
    uo[u * 65 + d] = fmaxf(a1, 0.f);
    io[u * 65 + d] = fmaxf(a2, 0.f);
  }
  __syncthreads();
  for (int i = tid; i < RR * DD; i += 256) {
    int u = i >> 6, e = i & 63;
    float a = 0.f;
    for (int d2 = 0; d2 < DD; ++d2) a += uo[u * 65 + d2] * ra_M[d2 * DD + e];
    au[u * 65 + e] = a;
  }
  __syncthreads();
  for (int i = tid; i < RR * RR; i += 256) {
    int u = i / RR, v = i % RR;
    float a = 0.f;
    for (int e = 0; e < DD; ++e) a += au[u * 65 + e] * io[v * 65 + e];
    sc[u * 21 + v] = a;
  }
  __syncthreads();
  if (tid < RR) {
    float m = -INFINITY;
    for (int v = 0; v < RR; ++v) m = fmaxf(m, sc[tid * 21 + v]);
    rl[tid] = m;
  } else if (tid >= 64 && tid < 64 + RR) {
    int v = tid - 64;
    float m = -INFINITY;
    for (int u = 0; u < RR; ++u) m = fmaxf(m, sc[u * 21 + v]);
    cl[v] = m;
  }
  __syncthreads();
  if (tid < 4 * RR) {
    int n = tid / RR, r = tid % RR;
    uint32_t k0, k1, o0, o1;
    tf2x32(0u, 42u, 0u, (uint32_t)n, k0, k1);       // fold_in(key(42), n)
    int e = b * RR + r;
    tf2x32(k0, k1, 0u, (uint32_t)e, o0, o1);        // partitionable threefry
    uint32_t bits = o0 ^ o1;
    float u01 = __uint_as_float((bits >> 9) | 0x3f800000u) - 1.0f;
    const float TINY = 1.1754943508222875e-38f;
    float u = fmaxf(u01 + TINY, TINY);
    float g = -logf(-logf(u));
    gval[n][r] = ((n & 1) ? cl[r] : rl[r]) + g;
  }
  __syncthreads();
  if (tid < 4) {
    float best = -INFINITY; int arg = 0;
    for (int r = 0; r < RR; ++r) {                   // serial: first-max tie-break
      float v = gval[tid][r];
      if (v > best) { best = v; arg = r; }
    }
    sel[tid * BB + b] = arg;
  }
}

// ---------------- K3: word-level attention via tables ----------------
__global__ __launch_bounds__(256) void word_coatt(
    const int* __restrict__ uidx, const int* __restrict__ iidx,
    const float* __restrict__ emb,
    const float* __restrict__ E1, const float* __restrict__ E2,
    const int* __restrict__ sel, float* __restrict__ x) {
  int bid = blockIdx.x;
  int p = bid >> 9, b = bid & (BB - 1);
  int ru = sel[(2 * p) * BB + b];
  int rv = sel[(2 * p + 1) * BB + b];
  __shared__ int uw[LL], iw[LL];
  __shared__ float E1u[LL * 65], E2i[LL * 65];
  __shared__ float ubar[DD], zbar[DD];
  __shared__ float rm[LL], cm[LL];
  int tid = threadIdx.x;
  if (tid < LL) uw[tid] = uidx[((size_t)b * RR + ru) * LL + tid];
  else if (tid >= 64 && tid < 64 + LL) iw[tid - 64] = iidx[((size_t)b * RR + rv) * LL + (tid - 64)];
  __syncthreads();
  for (int i = tid; i < LL * DD; i += 256) {
    int l = i >> 6, d = i & 63;
    E1u[l * 65 + d] = E1[(size_t)uw[l] * DD + d];
    E2i[l * 65 + d] = E2[(size_t)iw[l] * DD + d];
  }
  __syncthreads();
  if (tid < DD) {
    float s = 0.f;
    for (int l = 0; l < LL; ++l) s += E1u[l * 65 + tid];
    ubar[tid] = s / 50.f;
  } else if (tid < 128) {
    int d = tid - 64;
    float s = 0.f;
    for (int l = 0; l < LL; ++l) s += E2i[l * 65 + d];
    zbar[d] = s / 50.f;
  }
  __syncthreads();
  if (tid < LL) {
    float a = 0.f;
    for (int e = 0; e < DD; ++e) a += E1u[tid * 65 + e] * zbar[e];
    rm[tid] = a;
  } else if (tid >= 64 && tid < 64 + LL) {
    int lj = tid - 64;
    float a = 0.f;
    for (int e = 0; e < DD; ++e) a += ubar[e] * E2i[lj * 65 + e];
    cm[lj] = a;
  }
  __syncthreads();
  int w = tid >> 6, lane = tid & 63;
  if (w == 0) {
    float v = (lane < LL) ? rm[lane] : -INFINITY;
    float m = wave_max(v);
    float ex = (lane < LL) ? expf(rm[lane] - m) : 0.f;
    float sm = wave_sum(ex);
    if (lane < LL) rm[lane] = ex / sm;
  } else if (w == 1) {
    float v = (lane < LL) ? cm[lane] : -INFINITY;
    float m = wave_max(v);
    float ex = (lane < LL) ? expf(cm[lane] - m) : 0.f;
    float sm = wave_sum(ex);
    if (lane < LL) cm[lane] = ex / sm;
  }
  __syncthreads();
  if (w == 0) {
    float a = 0.f;
    for (int l = 0; l < LL; ++l) a += rm[l] * emb[(size_t)uw[l] * DD + lane];
    x[(size_t)b * IN_DIM + p * DD + lane] = a;
  } else if (w == 1) {
    float a = 0.f;
    for (int l = 0; l < LL; ++l) a += cm[l] * emb[(size_t)iw[l] * DD + lane];
    x[(size_t)b * IN_DIM + 2 * DD + p * DD + lane] = a;
  }
}

// ---------------- K4: FM head (wave per sample) ----------------
// grid = 128 blocks, 256 threads; b = blockIdx.x*4 + wave
__global__ __launch_bounds__(256) void fm_head(
    const float* __restrict__ x, const float* __restrict__ fm_v,
    const float* __restrict__ fm_w, const float* __restrict__ fm_b,
    float* __restrict__ out) {
  int tid = threadIdx.x;
  int w = tid >> 6, lane = tid & 63;
  int b = blockIdx.x * 4 + w;
  const float* xb = x + (size_t)b * IN_DIM;
  float4 xv4 = *reinterpret_cast<const float4*>(&xb[lane * 4]);
  float4 wv4 = *reinterpret_cast<const float4*>(&fm_w[lane * 4]);
  float xa[4] = {xv4.x, xv4.y, xv4.z, xv4.w};
  float wa[4] = {wv4.x, wv4.y, wv4.z, wv4.w};
  float lin = 0.f;
  float i1[KK], i2[KK];
#pragma unroll
  for (int k = 0; k < KK; ++k) { i1[k] = 0.f; i2[k] = 0.f; }
#pragma unroll
  for (int jj = 0; jj < 4; ++jj) {
    float xj = xa[jj];
    lin += xj * wa[jj];
    float x2 = xj * xj;
    const float* vr = fm_v + (size_t)(lane * 4 + jj) * KK;
#pragma unroll
    for (int k = 0; k < KK; ++k) {
      float v = vr[k];
      i1[k] += xj * v;
      i2[k] += x2 * (v * v);
    }
  }
  lin = wave_sum(lin);
  float pair = 0.f;
#pragma unroll
  for (int k = 0; k < KK; ++k) {
    float s1 = wave_sum(i1[k]);
    float s2 = wave_sum(i2[k]);
    pair += s1 * s1 - s2;
  }
  if (lane == 0) out[b] = (lin + fm_b[0]) + 0.5f * pair;
}

extern "C" void kernel_launch(void* const* d_in, const int* in_sizes, int n_in,
                              void* d_out, int out_size, void* d_ws, size_t ws_size,
                              hipStream_t stream) {
  (void)in_sizes; (void)n_in; (void)out_size; (void)ws_size;
  const int*   user_reviews = (const int*)d_in[0];
  const int*   item_reviews = (const int*)d_in[1];
  const float* emb  = (const float*)d_in[2];
  const float* gw1  = (const float*)d_in[3];
  const float* gw2  = (const float*)d_in[4];
  const float* gb2  = (const float*)d_in[5];
  const float* gbg  = (const float*)d_in[6];
  const float* ra_w = (const float*)d_in[7];
  const float* ra_b = (const float*)d_in[8];
  const float* ra_M = (const float*)d_in[9];
  const float* wa_w = (const float*)d_in[10];
  const float* wa_b = (const float*)d_in[11];
  const float* wa_M = (const float*)d_in[12];
  const float* fm_v = (const float*)d_in[13];
  const float* fm_w = (const float*)d_in[14];
  const float* fm_b = (const float*)d_in[15];
  float* out = (float*)d_out;

  float* ws = (float*)d_ws;
  float* u_rev = ws;                        // B*R*D = 655360
  float* i_rev = u_rev + BB * RR * DD;      // 655360
  float* x     = i_rev + BB * RR * DD;      // B*256 = 131072
  float* w1T   = x + BB * IN_DIM;           // 4096 each
  float* w2T   = w1T + DD * DD;
  float* raT   = w2T + DD * DD;
  float* waT   = raT + DD * DD;
  float* maT   = waT + DD * DD;
  float* E1    = maT + DD * DD;             // V*D = 3.2M
  float* E2    = E1 + (size_t)VV * DD;      // V*D = 3.2M
  int*   sel   = (int*)(E2 + (size_t)VV * DD);  // 4*B ints

  transpose_w<<<dim3(16), dim3(256), 0, stream>>>(gw1, gw2, ra_w, wa_w, wa_M,
                                                  w1T, w2T, raT, waT, maT);
  build_tables<<<dim3(VV / 16), dim3(256), 0, stream>>>(emb, waT, wa_b, maT, E1, E2);
  embed_gate<<<dim3(1280), dim3(256), 0, stream>>>(
      user_reviews, item_reviews, emb, w1T, w2T, gb2, gbg, u_rev, i_rev);
  coatt_rev_sel<<<dim3(BB), dim3(256), 0, stream>>>(
      u_rev, i_rev, raT, ra_b, ra_M, sel);
  word_coatt<<<dim3(PP * BB), dim3(256), 0, stream>>>(
      user_reviews, item_reviews, emb, E1, E2, sel, x);
  fm_head<<<dim3(128), dim3(256), 0, stream>>>(x, fm_v, fm_w, fm_b, out);
}

// Round 6
// 101.467 us; speedup vs baseline: 2.7811x; 1.3113x over previous
//
#include <hip/hip_runtime.h>
#include <stdint.h>
#include <math.h>

#define BB 512
#define RR 20
#define LL 50
#define DD 64
#define PP 2
#define KK 10
#define IN_DIM 256   // 2*P*D
#define VV 50000

// ---------------- threefry2x32 (bit-exact JAX) ----------------
__device__ __forceinline__ uint32_t rotl32(uint32_t v, int d) {
  return (v << d) | (v >> (32 - d));
}

__device__ __forceinline__ void tf2x32(uint32_t k0, uint32_t k1,
                                       uint32_t x0, uint32_t x1,
                                       uint32_t& o0, uint32_t& o1) {
  uint32_t ks0 = k0, ks1 = k1, ks2 = k0 ^ k1 ^ 0x1BD11BDAu;
  x0 += ks0; x1 += ks1;
#define TF_RND(r) { x0 += x1; x1 = rotl32(x1, r); x1 ^= x0; }
  TF_RND(13) TF_RND(15) TF_RND(26) TF_RND(6)
  x0 += ks1; x1 += ks2 + 1u;
  TF_RND(17) TF_RND(29) TF_RND(16) TF_RND(24)
  x0 += ks2; x1 += ks0 + 2u;
  TF_RND(13) TF_RND(15) TF_RND(26) TF_RND(6)
  x0 += ks0; x1 += ks1 + 3u;
  TF_RND(17) TF_RND(29) TF_RND(16) TF_RND(24)
  x0 += ks1; x1 += ks2 + 4u;
  TF_RND(13) TF_RND(15) TF_RND(26) TF_RND(6)
  x0 += ks2; x1 += ks0 + 5u;
#undef TF_RND
  o0 = x0; o1 = x1;
}

__device__ __forceinline__ float wave_sum(float v) {
  for (int off = 32; off; off >>= 1) v += __shfl_xor(v, off, 64);
  return v;
}
__device__ __forceinline__ float wave_max(float v) {
  for (int off = 32; off; off >>= 1) v = fmaxf(v, __shfl_xor(v, off, 64));
  return v;
}

// ---------------- K0: transpose the 64x64 weight matrices ----------------
__global__ __launch_bounds__(256) void transpose_w(
    const float* __restrict__ w1, const float* __restrict__ w2,
    const float* __restrict__ ra, const float* __restrict__ wa,
    const float* __restrict__ ma,
    float* __restrict__ w1T, float* __restrict__ w2T,
    float* __restrict__ raT, float* __restrict__ waT,
    float* __restrict__ maT) {
  int i = blockIdx.x * 256 + threadIdx.x;
  if (i < DD * DD) {
    int r = i >> 6, c = i & 63;
    w1T[c * DD + r] = w1[i];
    w2T[c * DD + r] = w2[i];
    raT[c * DD + r] = ra[i];
    waT[c * DD + r] = wa[i];
    maT[c * DD + r] = ma[i];
  }
}

// ---------------- K0b: tables as LDS-tiled register GEMM ----------------
// grid = ceil(V/64) blocks, 256 threads. Block computes 64 words x 64 dims.
// Thread (wq = tid&15, dq = tid>>4) owns words wq*4..+3, dims dq*4..+3 (4x4 acc).
// Phase 1: E1 = relu(emb @ waT + b); Phase 2: E2 = E1 @ maT.
__global__ __launch_bounds__(256) void build_tables(
    const float* __restrict__ emb, const float* __restrict__ waT,
    const float* __restrict__ wa_b, const float* __restrict__ maT,
    float* __restrict__ E1, float* __restrict__ E2) {
  __shared__ float A[DD * 68];   // AsT[k][w] (emb panel transposed); reused as RsT[d][w]
  __shared__ float Bs[DD * 68];  // B[k][d]: waT rows, then maT rows
  int tid = threadIdx.x;
  int v0 = blockIdx.x * 64;
  // ---- stage A transposed (coalesced global read, transposed LDS write) ----
  {
    int w = tid >> 4;              // 0..15
    int k0 = (tid & 15) * 4;
    for (int rep = 0; rep < 4; ++rep) {
      int wr = rep * 16 + w;       // 0..63
      int v = v0 + wr;
      float4 e4 = {0.f, 0.f, 0.f, 0.f};
      if (v < VV) e4 = *reinterpret_cast<const float4*>(&emb[(size_t)v * DD + k0]);
      A[(k0 + 0) * 68 + wr] = e4.x;
      A[(k0 + 1) * 68 + wr] = e4.y;
      A[(k0 + 2) * 68 + wr] = e4.z;
      A[(k0 + 3) * 68 + wr] = e4.w;
    }
  }
  // ---- stage Bs = waT ----
  for (int i = tid; i < DD * 16; i += 256) {
    int k = i >> 4, c = i & 15;
    *reinterpret_cast<float4*>(&Bs[k * 68 + c * 4]) =
        *reinterpret_cast<const float4*>(&waT[k * DD + c * 4]);
  }
  __syncthreads();
  int wq = tid & 15, dq = tid >> 4;
  float4 bias = *reinterpret_cast<const float4*>(&wa_b[dq * 4]);
  float acc[4][4];
#pragma unroll
  for (int i = 0; i < 4; ++i) {
    acc[i][0] = bias.x; acc[i][1] = bias.y; acc[i][2] = bias.z; acc[i][3] = bias.w;
  }
  for (int k = 0; k < DD; ++k) {
    float4 a4 = *reinterpret_cast<const float4*>(&A[k * 68 + wq * 4]);
    float4 b4 = *reinterpret_cast<const float4*>(&Bs[k * 68 + dq * 4]);
    float av[4] = {a4.x, a4.y, a4.z, a4.w};
    float bv[4] = {b4.x, b4.y, b4.z, b4.w};
#pragma unroll
    for (int i = 0; i < 4; ++i)
#pragma unroll
      for (int j = 0; j < 4; ++j) acc[i][j] += av[i] * bv[j];
  }
#pragma unroll
  for (int i = 0; i < 4; ++i)
#pragma unroll
    for (int j = 0; j < 4; ++j) acc[i][j] = fmaxf(acc[i][j], 0.f);
  // write E1 (guarded)
#pragma unroll
  for (int i = 0; i < 4; ++i) {
    int v = v0 + wq * 4 + i;
    if (v < VV) {
      float4 r = {acc[i][0], acc[i][1], acc[i][2], acc[i][3]};
      *reinterpret_cast<float4*>(&E1[(size_t)v * DD + dq * 4]) = r;
    }
  }
  __syncthreads();   // everyone done reading A and Bs
  // RsT[d][w] = relu value; restage Bs = maT
#pragma unroll
  for (int j = 0; j < 4; ++j)
#pragma unroll
    for (int i = 0; i < 4; ++i)
      A[(dq * 4 + j) * 68 + wq * 4 + i] = acc[i][j];
  for (int i = tid; i < DD * 16; i += 256) {
    int k = i >> 4, c = i & 15;
    *reinterpret_cast<float4*>(&Bs[k * 68 + c * 4]) =
        *reinterpret_cast<const float4*>(&maT[k * DD + c * 4]);
  }
  __syncthreads();
  float acc2[4][4];
#pragma unroll
  for (int i = 0; i < 4; ++i)
#pragma unroll
    for (int j = 0; j < 4; ++j) acc2[i][j] = 0.f;
  for (int k = 0; k < DD; ++k) {
    float4 a4 = *reinterpret_cast<const float4*>(&A[k * 68 + wq * 4]);
    float4 b4 = *reinterpret_cast<const float4*>(&Bs[k * 68 + dq * 4]);
    float av[4] = {a4.x, a4.y, a4.z, a4.w};
    float bv[4] = {b4.x, b4.y, b4.z, b4.w};
#pragma unroll
    for (int i = 0; i < 4; ++i)
#pragma unroll
      for (int j = 0; j < 4; ++j) acc2[i][j] += av[i] * bv[j];
  }
#pragma unroll
  for (int i = 0; i < 4; ++i) {
    int v = v0 + wq * 4 + i;
    if (v < VV) {
      float4 r = {acc2[i][0], acc2[i][1], acc2[i][2], acc2[i][3]};
      *reinterpret_cast<float4*>(&E2[(size_t)v * DD + dq * 4]) = r;
    }
  }
}

// ---------------- K1: embedding sum + gating ----------------
// grid = 1280 blocks (16 reviews each: blocks 0..639 user, 640..1279 item)
__global__ __launch_bounds__(256) void embed_gate(
    const int* __restrict__ uidx, const int* __restrict__ iidx,
    const float* __restrict__ emb,
    const float* __restrict__ w1T, const float* __restrict__ w2T,
    const float* __restrict__ b2, const float* __restrict__ bg,
    float* __restrict__ u_rev, float* __restrict__ i_rev) {
  __shared__ int idxs[16 * LL];
  __shared__ float us[16][68];
  int tid = threadIdx.x;
  int isItem = (blockIdx.x >= 640);
  const int* src = isItem ? (iidx + (size_t)(blockIdx.x - 640) * 16 * LL)
                          : (uidx + (size_t)blockIdx.x * 16 * LL);
  for (int i = tid; i < 16 * LL; i += 256) idxs[i] = src[i];
  __syncthreads();
  int w = tid >> 6, lane = tid & 63;
  int grp = lane >> 4, q = lane & 15;
  int revl = w * 4 + grp;
  const int* myidx = idxs + revl * LL;
  float4 acc = {0.f, 0.f, 0.f, 0.f};
  for (int l = 0; l < LL; ++l) {               // l-sequential (matches reference)
    int v = myidx[l];
    float4 e4 = *reinterpret_cast<const float4*>(&emb[(size_t)v * DD + q * 4]);
    acc.x += e4.x; acc.y += e4.y; acc.z += e4.z; acc.w += e4.w;
  }
  *reinterpret_cast<float4*>(&us[revl][q * 4]) = acc;
  __syncthreads();
  float4 d1 = {0.f, 0.f, 0.f, 0.f}, d2 = {0.f, 0.f, 0.f, 0.f};
  for (int e = 0; e < DD; ++e) {
    float xv = us[revl][e];                    // LDS broadcast
    float4 w1v = *reinterpret_cast<const float4*>(&w1T[e * DD + q * 4]);
    float4 w2v = *reinterpret_cast<const float4*>(&w2T[e * DD + q * 4]);
    d1.x += xv * w1v.x; d1.y += xv * w1v.y; d1.z += xv * w1v.z; d1.w += xv * w1v.w;
    d2.x += xv * w2v.x; d2.y += xv * w2v.y; d2.z += xv * w2v.z; d2.w += xv * w2v.w;
  }
  float4 b2v = *reinterpret_cast<const float4*>(&b2[q * 4]);
  float4 bgv = *reinterpret_cast<const float4*>(&bg[q * 4]);
  float4 val;
  val.x = 1.f / (1.f + expf(-d1.x)) + bgv.x * tanhf(d2.x + b2v.x);
  val.y = 1.f / (1.f + expf(-d1.y)) + bgv.y * tanhf(d2.y + b2v.y);
  val.z = 1.f / (1.f + expf(-d1.z)) + bgv.z * tanhf(d2.z + b2v.z);
  val.w = 1.f / (1.f + expf(-d1.w)) + bgv.w * tanhf(d2.w + b2v.w);
  int gid = blockIdx.x * 16 + revl;
  int t = gid % (BB * RR);
  float* dst = (gid >= BB * RR) ? i_rev : u_rev;
  *reinterpret_cast<float4*>(&dst[(size_t)t * DD + q * 4]) = val;
}

// ---------------- K2: review co-attention + gumbel selection (BIT-IDENTICAL, untouched) ----------------
__global__ __launch_bounds__(256) void coatt_rev_sel(
    const float* __restrict__ u_rev, const float* __restrict__ i_rev,
    const float* __restrict__ raT, const float* __restrict__ ra_b,
    const float* __restrict__ ra_M, int* __restrict__ sel) {
  int b = blockIdx.x;
  __shared__ float ur[RR * 65], ir[RR * 65], uo[RR * 65], io[RR * 65], au[RR * 65];
  __shared__ float sc[RR * 21];
  __shared__ float rl[RR], cl[RR];
  __shared__ float gval[4][RR];
  int tid = threadIdx.x;
  for (int i = tid; i < RR * DD; i += 256) {
    int r = i >> 6, d = i & 63;
    ur[r * 65 + d] = u_rev[(size_t)b * RR * DD + i];
    ir[r * 65 + d] = i_rev[(size_t)b * RR * DD + i];
  }
  __syncthreads();
  for (int i = tid; i < RR * DD; i += 256) {
    int u = i >> 6, d = i & 63;
    float bb = ra_b[d];
    float a1 = bb, a2 = bb;
    for (int e = 0; e < DD; ++e) {
      float wv = raT[e * DD + d];
      a1 += ur[u * 65 + e] * wv;
      a2 += ir[u * 65 + e] * wv;
    }
    uo[u * 65 + d] = fmaxf(a1, 0.f);
    io[u * 65 + d] = fmaxf(a2, 0.f);
  }
  __syncthreads();
  for (int i = tid; i < RR * DD; i += 256) {
    int u = i >> 6, e = i & 63;
    float a = 0.f;
    for (int d2 = 0; d2 < DD; ++d2) a += uo[u * 65 + d2] * ra_M[d2 * DD + e];
    au[u * 65 + e] = a;
  }
  __syncthreads();
  for (int i = tid; i < RR * RR; i += 256) {
    int u = i / RR, v = i % RR;
    float a = 0.f;
    for (int e = 0; e < DD; ++e) a += au[u * 65 + e] * io[v * 65 + e];
    sc[u * 21 + v] = a;
  }
  __syncthreads();
  if (tid < RR) {
    float m = -INFINITY;
    for (int v = 0; v < RR; ++v) m = fmaxf(m, sc[tid * 21 + v]);
    rl[tid] = m;
  } else if (tid >= 64 && tid < 64 + RR) {
    int v = tid - 64;
    float m = -INFINITY;
    for (int u = 0; u < RR; ++u) m = fmaxf(m, sc[u * 21 + v]);
    cl[v] = m;
  }
  __syncthreads();
  if (tid < 4 * RR) {
    int n = tid / RR, r = tid % RR;
    uint32_t k0, k1, o0, o1;
    tf2x32(0u, 42u, 0u, (uint32_t)n, k0, k1);       // fold_in(key(42), n)
    int e = b * RR + r;
    tf2x32(k0, k1, 0u, (uint32_t)e, o0, o1);        // partitionable threefry
    uint32_t bits = o0 ^ o1;
    float u01 = __uint_as_float((bits >> 9) | 0x3f800000u) - 1.0f;
    const float TINY = 1.1754943508222875e-38f;
    float u = fmaxf(u01 + TINY, TINY);
    float g = -logf(-logf(u));
    gval[n][r] = ((n & 1) ? cl[r] : rl[r]) + g;
  }
  __syncthreads();
  if (tid < 4) {
    float best = -INFINITY; int arg = 0;
    for (int r = 0; r < RR; ++r) {                   // serial: first-max tie-break
      float v = gval[tid][r];
      if (v > best) { best = v; arg = r; }
    }
    sel[tid * BB + b] = arg;
  }
}

// ---------------- K3: word-level attention via tables ----------------
__global__ __launch_bounds__(256) void word_coatt(
    const int* __restrict__ uidx, const int* __restrict__ iidx,
    const float* __restrict__ emb,
    const float* __restrict__ E1, const float* __restrict__ E2,
    const int* __restrict__ sel, float* __restrict__ x) {
  int bid = blockIdx.x;
  int p = bid >> 9, b = bid & (BB - 1);
  int ru = sel[(2 * p) * BB + b];
  int rv = sel[(2 * p + 1) * BB + b];
  __shared__ int uw[LL], iw[LL];
  __shared__ float E1u[LL * 65], E2i[LL * 65];
  __shared__ float ubar[DD], zbar[DD];
  __shared__ float rm[LL], cm[LL];
  int tid = threadIdx.x;
  if (tid < LL) uw[tid] = uidx[((size_t)b * RR + ru) * LL + tid];
  else if (tid >= 64 && tid < 64 + LL) iw[tid - 64] = iidx[((size_t)b * RR + rv) * LL + (tid - 64)];
  __syncthreads();
  for (int i = tid; i < LL * DD; i += 256) {
    int l = i >> 6, d = i & 63;
    E1u[l * 65 + d] = E1[(size_t)uw[l] * DD + d];
    E2i[l * 65 + d] = E2[(size_t)iw[l] * DD + d];
  }
  __syncthreads();
  if (tid < DD) {
    float s = 0.f;
    for (int l = 0; l < LL; ++l) s += E1u[l * 65 + tid];
    ubar[tid] = s / 50.f;
  } else if (tid < 128) {
    int d = tid - 64;
    float s = 0.f;
    for (int l = 0; l < LL; ++l) s += E2i[l * 65 + d];
    zbar[d] = s / 50.f;
  }
  __syncthreads();
  if (tid < LL) {
    float a = 0.f;
    for (int e = 0; e < DD; ++e) a += E1u[tid * 65 + e] * zbar[e];
    rm[tid] = a;
  } else if (tid >= 64 && tid < 64 + LL) {
    int lj = tid - 64;
    float a = 0.f;
    for (int e = 0; e < DD; ++e) a += ubar[e] * E2i[lj * 65 + e];
    cm[lj] = a;
  }
  __syncthreads();
  int w = tid >> 6, lane = tid & 63;
  if (w == 0) {
    float v = (lane < LL) ? rm[lane] : -INFINITY;
    float m = wave_max(v);
    float ex = (lane < LL) ? expf(rm[lane] - m) : 0.f;
    float sm = wave_sum(ex);
    if (lane < LL) rm[lane] = ex / sm;
  } else if (w == 1) {
    float v = (lane < LL) ? cm[lane] : -INFINITY;
    float m = wave_max(v);
    float ex = (lane < LL) ? expf(cm[lane] - m) : 0.f;
    float sm = wave_sum(ex);
    if (lane < LL) cm[lane] = ex / sm;
  }
  __syncthreads();
  if (w == 0) {
    float a = 0.f;
    for (int l = 0; l < LL; ++l) a += rm[l] * emb[(size_t)uw[l] * DD + lane];
    x[(size_t)b * IN_DIM + p * DD + lane] = a;
  } else if (w == 1) {
    float a = 0.f;
    for (int l = 0; l < LL; ++l) a += cm[l] * emb[(size_t)iw[l] * DD + lane];
    x[(size_t)b * IN_DIM + 2 * DD + p * DD + lane] = a;
  }
}

// ---------------- K4: FM head (wave per sample) ----------------
__global__ __launch_bounds__(256) void fm_head(
    const float* __restrict__ x, const float* __restrict__ fm_v,
    const float* __restrict__ fm_w, const float* __restrict__ fm_b,
    float* __restrict__ out) {
  int tid = threadIdx.x;
  int w = tid >> 6, lane = tid & 63;
  int b = blockIdx.x * 4 + w;
  const float* xb = x + (size_t)b * IN_DIM;
  float4 xv4 = *reinterpret_cast<const float4*>(&xb[lane * 4]);
  float4 wv4 = *reinterpret_cast<const float4*>(&fm_w[lane * 4]);
  float xa[4] = {xv4.x, xv4.y, xv4.z, xv4.w};
  float wa[4] = {wv4.x, wv4.y, wv4.z, wv4.w};
  float lin = 0.f;
  float i1[KK], i2[KK];
#pragma unroll
  for (int k = 0; k < KK; ++k) { i1[k] = 0.f; i2[k] = 0.f; }
#pragma unroll
  for (int jj = 0; jj < 4; ++jj) {
    float xj = xa[jj];
    lin += xj * wa[jj];
    float x2 = xj * xj;
    const float* vr = fm_v + (size_t)(lane * 4 + jj) * KK;
#pragma unroll
    for (int k = 0; k < KK; ++k) {
      float v = vr[k];
      i1[k] += xj * v;
      i2[k] += x2 * (v * v);
    }
  }
  lin = wave_sum(lin);
  float pair = 0.f;
#pragma unroll
  for (int k = 0; k < KK; ++k) {
    float s1 = wave_sum(i1[k]);
    float s2 = wave_sum(i2[k]);
    pair += s1 * s1 - s2;
  }
  if (lane == 0) out[b] = (lin + fm_b[0]) + 0.5f * pair;
}

extern "C" void kernel_launch(void* const* d_in, const int* in_sizes, int n_in,
                              void* d_out, int out_size, void* d_ws, size_t ws_size,
                              hipStream_t stream) {
  (void)in_sizes; (void)n_in; (void)out_size; (void)ws_size;
  const int*   user_reviews = (const int*)d_in[0];
  const int*   item_reviews = (const int*)d_in[1];
  const float* emb  = (const float*)d_in[2];
  const float* gw1  = (const float*)d_in[3];
  const float* gw2  = (const float*)d_in[4];
  const float* gb2  = (const float*)d_in[5];
  const float* gbg  = (const float*)d_in[6];
  const float* ra_w = (const float*)d_in[7];
  const float* ra_b = (const float*)d_in[8];
  const float* ra_M = (const float*)d_in[9];
  const float* wa_w = (const float*)d_in[10];
  const float* wa_b = (const float*)d_in[11];
  const float* wa_M = (const float*)d_in[12];
  const float* fm_v = (const float*)d_in[13];
  const float* fm_w = (const float*)d_in[14];
  const float* fm_b = (const float*)d_in[15];
  float* out = (float*)d_out;

  float* ws = (float*)d_ws;
  float* u_rev = ws;                        // B*R*D = 655360
  float* i_rev = u_rev + BB * RR * DD;      // 655360
  float* x     = i_rev + BB * RR * DD;      // B*256 = 131072
  float* w1T   = x + BB * IN_DIM;           // 4096 each
  float* w2T   = w1T + DD * DD;
  float* raT   = w2T + DD * DD;
  float* waT   = raT + DD * DD;
  float* maT   = waT + DD * DD;
  float* E1    = maT + DD * DD;             // V*D = 3.2M
  float* E2    = E1 + (size_t)VV * DD;      // V*D = 3.2M
  int*   sel   = (int*)(E2 + (size_t)VV * DD);  // 4*B ints

  transpose_w<<<dim3(16), dim3(256), 0, stream>>>(gw1, gw2, ra_w, wa_w, wa_M,
                                                  w1T, w2T, raT, waT, maT);
  build_tables<<<dim3((VV + 63) / 64), dim3(256), 0, stream>>>(emb, waT, wa_b, maT, E1, E2);
  embed_gate<<<dim3(1280), dim3(256), 0, stream>>>(
      user_reviews, item_reviews, emb, w1T, w2T, gb2, gbg, u_rev, i_rev);
  coatt_rev_sel<<<dim3(BB), dim3(256), 0, stream>>>(
      u_rev, i_rev, raT, ra_b, ra_M, sel);
  word_coatt<<<dim3(PP * BB), dim3(256), 0, stream>>>(
      user_reviews, item_reviews, emb, E1, E2, sel, x);
  fm_head<<<dim3(128), dim3(256), 0, stream>>>(x, fm_v, fm_w, fm_b, out);
}